// Round 4
// baseline (92.066 us; speedup 1.0000x reference)
//
#include <hip/hip_runtime.h>

#define HH   512
#define AA   128
#define SB   1024
#define BATCH 2

__device__ __forceinline__ float fast_rcp(float x) { return __builtin_amdgcn_rcpf(x); }
__device__ __forceinline__ float fast_ex2(float x) { return __builtin_amdgcn_exp2f(x); }

// K1: partial GEMM C = lstm(2048x512) @ [w|u](512x256), K split in 2 halves.
// NO LDS: A in registers (2 m-rows/thread, reloaded per 16-k chunk; all 4 waves
// read the same 8KB A-chunk -> L1 hits), B wave-uniform -> SGPR s_loads.
// 256 threads, BM=128, BN=16 (4 waves x 4 cols). grid (16, 16, 2).
// Blocks (0,0,z) also zero colw (k2's atomic target).
__global__ __launch_bounds__(256) void k1_gemm(const float* __restrict__ lstm,
                                               const float* __restrict__ w,
                                               const float* __restrict__ u,
                                               float* __restrict__ part0,
                                               float* __restrict__ part1,
                                               float* __restrict__ colw)
{
    const int t    = threadIdx.x;
    const int lane = t & 63;
    const int wv   = __builtin_amdgcn_readfirstlane(t >> 6);   // 0..3, wave-uniform
    const int bx = blockIdx.x, by = blockIdx.y, bz = blockIdx.z;
    const int m0 = bx * 128;
    const int n0 = by * 16 + wv * 4;                 // global col 0..255
    const float* __restrict__ Bsrc = (n0 < AA) ? w : u;
    const int nc = n0 & (AA - 1);

    if (bx == 0 && by == 0) {                        // zero colw (512 float4 total)
        float4 z4; z4.x = z4.y = z4.z = z4.w = 0.f;
        ((float4*)colw)[bz * 256 + t] = z4;
    }

    const int kz0 = bz * 256;
    const float* __restrict__ Arow0 = &lstm[(size_t)(m0 + lane) * HH + kz0];
    const float* __restrict__ Arow1 = Arow0 + (size_t)64 * HH;

    float acc0[4], acc1[4];
    #pragma unroll
    for (int c = 0; c < 4; ++c) { acc0[c] = 0.f; acc1[c] = 0.f; }

    for (int c = 0; c < 16; ++c) {
        const int kb = c * 16;
        float a0r[16], a1r[16];
        #pragma unroll
        for (int q = 0; q < 4; ++q) {
            *(float4*)&a0r[q * 4] = *(const float4*)&Arow0[kb + q * 4];
            *(float4*)&a1r[q * 4] = *(const float4*)&Arow1[kb + q * 4];
        }
        #pragma unroll
        for (int k = 0; k < 16; ++k) {
            const float4 bq = *(const float4*)&Bsrc[(size_t)(kz0 + kb + k) * AA + nc]; // s_load
            const float a0 = a0r[k];
            const float a1 = a1r[k];
            acc0[0] = fmaf(a0, bq.x, acc0[0]);
            acc0[1] = fmaf(a0, bq.y, acc0[1]);
            acc0[2] = fmaf(a0, bq.z, acc0[2]);
            acc0[3] = fmaf(a0, bq.w, acc0[3]);
            acc1[0] = fmaf(a1, bq.x, acc1[0]);
            acc1[1] = fmaf(a1, bq.y, acc1[1]);
            acc1[2] = fmaf(a1, bq.z, acc1[2]);
            acc1[3] = fmaf(a1, bq.w, acc1[3]);
        }
    }

    float* __restrict__ part = bz ? part1 : part0;
    float4 s0; s0.x = acc0[0]; s0.y = acc0[1]; s0.z = acc0[2]; s0.w = acc0[3];
    float4 s1; s1.x = acc1[0]; s1.y = acc1[1]; s1.z = acc1[2]; s1.w = acc1[3];
    *(float4*)&part[(size_t)(m0 + lane)      * 256 + n0] = s0;
    *(float4*)&part[(size_t)(m0 + lane + 64) * 256 + n0] = s1;
}

// K1b: [P|Q] = exp2(KK * (part0 + part1)). grid (512), 256 threads, float4/thread.
__global__ __launch_bounds__(256) void k1b_combine_exp(const float* __restrict__ part0,
                                                       const float* __restrict__ part1,
                                                       float* __restrict__ P,
                                                       float* __restrict__ Q)
{
    const float KK = 2.8853900817779268f;            // 2 * log2(e)
    const int idx = blockIdx.x * 256 + threadIdx.x;  // 0..131071 float4s
    const float4 c0 = ((const float4*)part0)[idx];
    const float4 c1 = ((const float4*)part1)[idx];
    float4 o;
    o.x = fast_ex2(KK * (c0.x + c1.x));
    o.y = fast_ex2(KK * (c0.y + c1.y));
    o.z = fast_ex2(KK * (c0.z + c1.z));
    o.w = fast_ex2(KK * (c0.w + c1.w));
    const int m  = idx >> 6;                          // row 0..2047
    const int qd = idx & 63;                          // float4 within 256-col row
    float* dst = (qd < 32) ? &P[(size_t)m * AA + qd * 4]
                           : &Q[(size_t)m * AA + (qd - 32) * 4];
    *(float4*)dst = o;
}

// K2: fused e-score + softmax + colsum.
// Block = 4 i-rows x 1024 j (512 threads, 2 j each: t and t+512). grid (256, 2).
// 4-way rcp combine: sum_{4a} v_a/d_a = N/(d0 d1 d2 d3), one rcp per 4 elems.
// P rows + v wave-uniform -> SGPR s_loads; Q per-thread vector loads (L2-res).
// E kept in regs, row-sums block-reduced, attn written once, colw via atomics.
// Blocks x==0 zero ctx (k4's atomic target).
__global__ __launch_bounds__(512) void k2_fused(const float* __restrict__ P,
                                                const float* __restrict__ Q,
                                                const float* __restrict__ v,
                                                float* __restrict__ attn,
                                                float* __restrict__ colw,
                                                float* __restrict__ ctx)
{
    const int b  = blockIdx.y;
    const int i0 = blockIdx.x * 4;
    const int t  = threadIdx.x;                      // 0..511

    if (blockIdx.x == 0) ctx[b * HH + t] = 0.f;      // k4 runs after k2

    const float* __restrict__ Qr0 = &Q[((size_t)b * SB + t)       * AA];
    const float* __restrict__ Qr1 = &Q[((size_t)b * SB + t + 512) * AA];
    const float* __restrict__ Pb  = &P[((size_t)b * SB + i0)      * AA];

    float acc[4][2];
    #pragma unroll
    for (int i = 0; i < 4; ++i) { acc[i][0] = 0.f; acc[i][1] = 0.f; }
    float Vacc = 0.f;

    #pragma unroll 2
    for (int x = 0; x < 32; ++x) {
        const float4 q0 = *(const float4*)&Qr0[x * 4];
        const float4 q1 = *(const float4*)&Qr1[x * 4];
        const float4 vv = *(const float4*)&v[x * 4];          // s_load (uniform)
        Vacc += (vv.x + vv.y) + (vv.z + vv.w);
        #pragma unroll
        for (int i = 0; i < 4; ++i) {
            const float4 p = *(const float4*)&Pb[i * AA + x * 4];  // s_load (uniform)
            {   // j = t
                const float d0 = fmaf(p.x, q0.x, 1.0f);
                const float d1 = fmaf(p.y, q0.y, 1.0f);
                const float d2 = fmaf(p.z, q0.z, 1.0f);
                const float d3 = fmaf(p.w, q0.w, 1.0f);
                const float p01 = d0 * d1, p23 = d2 * d3;
                const float na = fmaf(vv.x, d1, vv.y * d0);
                const float nb = fmaf(vv.z, d3, vv.w * d2);
                const float N  = fmaf(nb, p01, na * p23);
                const float r  = fast_rcp(p01 * p23);
                acc[i][0] = fmaf(N, r, acc[i][0]);
            }
            {   // j = t + 512
                const float d0 = fmaf(p.x, q1.x, 1.0f);
                const float d1 = fmaf(p.y, q1.y, 1.0f);
                const float d2 = fmaf(p.z, q1.z, 1.0f);
                const float d3 = fmaf(p.w, q1.w, 1.0f);
                const float p01 = d0 * d1, p23 = d2 * d3;
                const float na = fmaf(vv.x, d1, vv.y * d0);
                const float nb = fmaf(vv.z, d3, vv.w * d2);
                const float N  = fmaf(nb, p01, na * p23);
                const float r  = fast_rcp(p01 * p23);
                acc[i][1] = fmaf(N, r, acc[i][1]);
            }
        }
    }

    // e = Vacc - 2*acc; E = exp2(L2E*Vacc - 2*L2E*acc). |e| <= ~9 -> no max pass.
    const float L2E  = 1.4426950408889634f;
    const float base = Vacc * L2E;
    float E[4][2];
    #pragma unroll
    for (int i = 0; i < 4; ++i) {
        E[i][0] = fast_ex2(fmaf(acc[i][0], -2.0f * L2E, base));
        E[i][1] = fast_ex2(fmaf(acc[i][1], -2.0f * L2E, base));
    }

    // cross-thread row sums (4 rows x 1024 j): wave reduce -> LDS -> all
    __shared__ float red[4][8];
    const int lane = t & 63, wvi = t >> 6;
    #pragma unroll
    for (int i = 0; i < 4; ++i) {
        float s = E[i][0] + E[i][1];
        #pragma unroll
        for (int off = 32; off > 0; off >>= 1) s += __shfl_xor(s, off);
        if (lane == 0) red[i][wvi] = s;
    }
    __syncthreads();

    float csum0 = 0.f, csum1 = 0.f;
    float* __restrict__ arow = &attn[((size_t)b * SB + i0) * SB];
    #pragma unroll
    for (int i = 0; i < 4; ++i) {
        const float4* rr = (const float4*)red[i];
        const float4 r0 = rr[0], r1 = rr[1];
        const float rs = ((r0.x + r0.y) + (r0.z + r0.w)) + ((r1.x + r1.y) + (r1.z + r1.w));
        const float inv = fast_rcp(rs);
        const float a0 = E[i][0] * inv;
        const float a1 = E[i][1] * inv;
        arow[(size_t)i * SB + t]       = a0;
        arow[(size_t)i * SB + t + 512] = a1;
        csum0 += a0;
        csum1 += a1;
    }
    atomicAdd(&colw[b * SB + t],       csum0);
    atomicAdd(&colw[b * SB + t + 512], csum1);
}

// K4: ctx[b,h] = sum_j colw[b,j] * lstm[b,j,h]. grid (2, 8, 2), 256 threads.
__global__ __launch_bounds__(256) void k4_context(const float* __restrict__ lstm,
                                                  const float* __restrict__ colw,
                                                  float* __restrict__ ctx)
{
    const int b  = blockIdx.z;
    const int h  = blockIdx.x * 256 + threadIdx.x;
    const int j0 = blockIdx.y * 128;
    __shared__ float cw[128];
    if (threadIdx.x < 128) cw[threadIdx.x] = colw[b * SB + j0 + threadIdx.x];
    __syncthreads();
    float acc = 0.f;
    #pragma unroll 8
    for (int jj = 0; jj < 128; ++jj)
        acc = fmaf(cw[jj], lstm[(size_t)(b * SB + j0 + jj) * HH + h], acc);
    atomicAdd(&ctx[b * HH + h], acc);
}

extern "C" void kernel_launch(void* const* d_in, const int* in_sizes, int n_in,
                              void* d_out, int out_size, void* d_ws, size_t ws_size,
                              hipStream_t stream)
{
    const float* lstm = (const float*)d_in[0];   // (B,S,H)
    const float* w    = (const float*)d_in[1];   // (H,A)
    const float* u    = (const float*)d_in[2];   // (H,A)
    const float* v    = (const float*)d_in[3];   // (A,)

    float* out  = (float*)d_out;
    float* ctx  = out;                     // (B,H)   = 1024 floats
    float* attn = out + BATCH * HH;        // (B,S,S) = 2M floats

    float* part0 = (float*)d_ws;                              // 2048*256 = 2 MB
    float* part1 = part0 + (size_t)2048 * 256;                // 2 MB
    float* P     = part1 + (size_t)2048 * 256;                // 1 MB
    float* Qb    = P     + (size_t)BATCH * SB * AA;           // 1 MB
    float* colw  = Qb    + (size_t)BATCH * SB * AA;           // 8 KB

    k1_gemm<<<dim3(16, 16, 2), 256, 0, stream>>>(lstm, w, u, part0, part1, colw);
    k1b_combine_exp<<<dim3(512), 256, 0, stream>>>(part0, part1, P, Qb);
    k2_fused<<<dim3(256, BATCH), 512, 0, stream>>>(P, Qb, v, attn, colw, ctx);
    k4_context<<<dim3(2, 8, BATCH), 256, 0, stream>>>(lstm, colw, ctx);
}

// Round 5
// 73.725 us; speedup vs baseline: 1.2488x; 1.2488x over previous
//
#include <hip/hip_runtime.h>

#define HH   512
#define AA   128
#define SB   1024
#define BATCH 2

__device__ __forceinline__ float fast_rcp(float x) { return __builtin_amdgcn_rcpf(x); }
__device__ __forceinline__ float fast_ex2(float x) { return __builtin_amdgcn_exp2f(x); }

// Sum over a quad: v0/d0+v1/d1+v2/d2+v3/d3 = (na*p23 + nb*p01) / (p01*p23),
// na = v0*d1+v1*d0, nb = v2*d3+v3*d2.  14 VALU + 1 rcp per 4 elements.
__device__ __forceinline__ void quad_acc(const float4 p, const float4 q4,
                                         const float4 vv, float& acc)
{
    const float d0 = fmaf(p.x, q4.x, 1.0f);
    const float d1 = fmaf(p.y, q4.y, 1.0f);
    const float d2 = fmaf(p.z, q4.z, 1.0f);
    const float d3 = fmaf(p.w, q4.w, 1.0f);
    const float p01 = d0 * d1, p23 = d2 * d3;
    const float na = fmaf(vv.x, d1, vv.y * d0);
    const float nb = fmaf(vv.z, d3, vv.w * d2);
    const float N  = fmaf(na, p23, nb * p01);
    acc = fmaf(N, fast_rcp(p01 * p23), acc);
}

// K1: partial GEMM C = lstm(2048x512) @ [w|u](512x256), K split 4 ways.
// BM=64, BN=64, BK=16, 256 threads, 4m x 4n per thread (LDS 24cyc < VALU 32cyc
// per k-step -> VALU-bound). grid (32, 4, 4) = 512 blocks (2/CU).
// All LDS access patterns are broadcast or 2-way (free). Also zeroes rsum/ctx.
__global__ __launch_bounds__(256) void k1_gemm(const float* __restrict__ lstm,
                                               const float* __restrict__ w,
                                               const float* __restrict__ u,
                                               float* __restrict__ parts,
                                               float* __restrict__ rsum,
                                               float* __restrict__ ctx)
{
    __shared__ float As[16][68];   // [k][m]
    __shared__ float Bs[16][68];   // [k][n]
    const int t  = threadIdx.x;
    const int bx = blockIdx.x, by = blockIdx.y, bz = blockIdx.z;
    const int m0 = bx * 64;
    const int n0 = by * 64;                        // global col 0..255
    const float* __restrict__ Bsrc = (n0 < AA) ? w : u;
    const int nc = n0 & (AA - 1);

    if (bx == 0) {                                 // zero atomic targets
        if (by == 0)      { rsum[bz * 512 + t] = 0.f; rsum[bz * 512 + 256 + t] = 0.f; }
        else if (by == 1) { ctx[bz * 256 + t] = 0.f; }
    }

    const int ar = t >> 2, aq = (t & 3) * 4;       // A staging: row, k-quad
    const int bk = t >> 4, bq = (t & 15) * 4;      // B staging: k, n-quad
    const int tm = (t >> 4) * 4, tn = (t & 15) * 4;

    float acc[4][4];
    #pragma unroll
    for (int mi = 0; mi < 4; ++mi)
        #pragma unroll
        for (int ni = 0; ni < 4; ++ni) acc[mi][ni] = 0.f;

    const int kz0 = bz * 128;
    for (int kc = 0; kc < 8; ++kc) {
        const int k0 = kz0 + kc * 16;
        const float4 a4 = *(const float4*)&lstm[(size_t)(m0 + ar) * HH + k0 + aq];
        const float4 b4 = *(const float4*)&Bsrc[(size_t)(k0 + bk) * AA + nc + bq];
        As[aq + 0][ar] = a4.x; As[aq + 1][ar] = a4.y;
        As[aq + 2][ar] = a4.z; As[aq + 3][ar] = a4.w;
        *(float4*)&Bs[bk][bq] = b4;
        __syncthreads();
        #pragma unroll
        for (int k = 0; k < 16; ++k) {
            const float4 av = *(const float4*)&As[k][tm];
            const float4 bv = *(const float4*)&Bs[k][tn];
            #pragma unroll
            for (int mi = 0; mi < 4; ++mi) {
                const float a = (mi == 0) ? av.x : (mi == 1) ? av.y : (mi == 2) ? av.z : av.w;
                acc[mi][0] = fmaf(a, bv.x, acc[mi][0]);
                acc[mi][1] = fmaf(a, bv.y, acc[mi][1]);
                acc[mi][2] = fmaf(a, bv.z, acc[mi][2]);
                acc[mi][3] = fmaf(a, bv.w, acc[mi][3]);
            }
        }
        __syncthreads();
    }

    float* __restrict__ part = parts + (size_t)bz * (2048 * 256);
    #pragma unroll
    for (int mi = 0; mi < 4; ++mi) {
        float4 s; s.x = acc[mi][0]; s.y = acc[mi][1]; s.z = acc[mi][2]; s.w = acc[mi][3];
        *(float4*)&part[(size_t)(m0 + tm + mi) * 256 + n0 + tn] = s;
    }
}

// K1b: [P|Q] = exp2(KK * (part0+part1+part2+part3)). grid (512), 256 threads.
__global__ __launch_bounds__(256) void k1b_combine_exp(const float* __restrict__ parts,
                                                       float* __restrict__ P,
                                                       float* __restrict__ Q)
{
    const float KK = 2.8853900817779268f;            // 2 * log2(e)
    const int idx = blockIdx.x * 256 + threadIdx.x;  // 0..131071 float4s
    const float4 c0 = ((const float4*)parts)[idx];
    const float4 c1 = ((const float4*)parts)[idx + 131072];
    const float4 c2 = ((const float4*)parts)[idx + 262144];
    const float4 c3 = ((const float4*)parts)[idx + 393216];
    float4 o;
    o.x = fast_ex2(KK * ((c0.x + c1.x) + (c2.x + c3.x)));
    o.y = fast_ex2(KK * ((c0.y + c1.y) + (c2.y + c3.y)));
    o.z = fast_ex2(KK * ((c0.z + c1.z) + (c2.z + c3.z)));
    o.w = fast_ex2(KK * ((c0.w + c1.w) + (c2.w + c3.w)));
    const int m  = idx >> 6;                          // row 0..2047
    const int qd = idx & 63;                          // float4 within 256-col row
    float* dst = (qd < 32) ? &P[(size_t)m * AA + qd * 4]
                           : &Q[(size_t)m * AA + (qd - 32) * 4];
    *(float4*)dst = o;
}

// K2a: E[b,i,j] = exp(e) into attn region + partial row sums via atomics.
// Thread owns one j; its full Q row lives in registers (chunk-prefetched,
// statically indexed). P rows + v stream on the scalar pipe (s_load).
// 8 i-rows/block, grid (4, 128, 2) = 1024 blocks (4/CU, 16 waves/CU).
__global__ __launch_bounds__(256) void k2a_escore(const float* __restrict__ P,
                                                  const float* __restrict__ Q,
                                                  const float* __restrict__ v,
                                                  float* __restrict__ E,
                                                  float* __restrict__ rsum)
{
    const int b  = blockIdx.z;
    const int i0 = blockIdx.y * 8;
    const int j  = blockIdx.x * 256 + threadIdx.x;

    const float4* __restrict__ Qr = (const float4*)&Q[((size_t)b * SB + j) * AA];
    const float*  __restrict__ Pb = &P[((size_t)b * SB + i0) * AA];

    float acc[8];
    #pragma unroll
    for (int i = 0; i < 8; ++i) acc[i] = 0.f;
    float Vacc = 0.f;

    float4 qc[4], qn[4];
    #pragma unroll
    for (int x2 = 0; x2 < 4; ++x2) qc[x2] = Qr[x2];

    for (int xc = 0; xc < 8; ++xc) {
        const int nb4 = (xc < 7) ? (xc + 1) * 4 : 0;   // last-iter dummy (re-reads 0..3)
        #pragma unroll
        for (int x2 = 0; x2 < 4; ++x2) qn[x2] = Qr[nb4 + x2];
        #pragma unroll
        for (int x2 = 0; x2 < 4; ++x2) {
            const float4 q4 = qc[x2];
            const float4 vv = *(const float4*)&v[(xc * 4 + x2) * 4];    // s_load
            Vacc += (vv.x + vv.y) + (vv.z + vv.w);
            #pragma unroll
            for (int i = 0; i < 8; ++i) {
                const float4 p = *(const float4*)&Pb[(size_t)i * AA + (xc * 4 + x2) * 4]; // s_load
                quad_acc(p, q4, vv, acc[i]);
            }
        }
        #pragma unroll
        for (int x2 = 0; x2 < 4; ++x2) qc[x2] = qn[x2];
    }

    // e = Vacc - 2*acc; E = exp2(L2E*Vacc - 2*L2E*acc). |e| <= ~9 -> no max pass.
    const float L2E  = 1.4426950408889634f;
    const float base = Vacc * L2E;
    float* __restrict__ Eout = &E[((size_t)(b * SB + i0)) * SB + j];
    const int lane = threadIdx.x & 63;
    #pragma unroll
    for (int i = 0; i < 8; ++i) {
        const float e = fast_ex2(fmaf(acc[i], -2.0f * L2E, base));
        Eout[(size_t)i * SB] = e;
        float s = e;
        #pragma unroll
        for (int off = 32; off > 0; off >>= 1) s += __shfl_xor(s, off);
        if (lane == 0) atomicAdd(&rsum[b * SB + i0 + i], s);
    }
}

// K2b: attn = E / rsum[row] in place + per-block column partials (non-atomic).
// Block = 8 rows x full 1024-j width (1024 threads). grid (128, 2).
__global__ __launch_bounds__(1024) void k2b_scale_colpart(float* __restrict__ attn,
                                                          const float* __restrict__ rsum,
                                                          float* __restrict__ colw_part)
{
    const int b  = blockIdx.y;
    const int i0 = blockIdx.x * 8;
    const int j  = threadIdx.x;

    float csum = 0.f;
    #pragma unroll
    for (int i = 0; i < 8; ++i) {
        const int row = b * SB + i0 + i;
        const float inv = fast_rcp(rsum[row]);            // s_load + rcp
        float* __restrict__ ap = &attn[(size_t)row * SB + j];
        const float a = (*ap) * inv;
        *ap = a;
        csum += a;
    }
    colw_part[((size_t)b * 128 + blockIdx.x) * SB + j] = csum;
}

// K4: ctx[b,h] = sum_j (sum_ic colw_part[b,ic,j]) * lstm[b,j,h].
// grid (2 hc, 32 jc, 2 b) = 128 blocks, 256 threads; 32 j per block.
__global__ __launch_bounds__(256) void k4_context(const float* __restrict__ lstm,
                                                  const float* __restrict__ colw_part,
                                                  float* __restrict__ ctx)
{
    const int b  = blockIdx.z;
    const int j0 = blockIdx.y * 32;
    const int h  = blockIdx.x * 256 + threadIdx.x;

    __shared__ float red[8][33];
    __shared__ float cw[32];
    const int jj = threadIdx.x & 31, grp = threadIdx.x >> 5;
    float s = 0.f;
    #pragma unroll
    for (int k2 = 0; k2 < 16; ++k2)
        s += colw_part[((size_t)b * 128 + grp * 16 + k2) * SB + j0 + jj];
    red[grp][jj] = s;
    __syncthreads();
    if (threadIdx.x < 32) {
        float c = 0.f;
        #pragma unroll
        for (int g = 0; g < 8; ++g) c += red[g][threadIdx.x];
        cw[threadIdx.x] = c;
    }
    __syncthreads();

    float acc = 0.f;
    #pragma unroll
    for (int x = 0; x < 32; ++x)
        acc = fmaf(cw[x], lstm[(size_t)(b * SB + j0 + x) * HH + h], acc);
    atomicAdd(&ctx[b * HH + h], acc);
}

extern "C" void kernel_launch(void* const* d_in, const int* in_sizes, int n_in,
                              void* d_out, int out_size, void* d_ws, size_t ws_size,
                              hipStream_t stream)
{
    const float* lstm = (const float*)d_in[0];   // (B,S,H)
    const float* w    = (const float*)d_in[1];   // (H,A)
    const float* u    = (const float*)d_in[2];   // (H,A)
    const float* v    = (const float*)d_in[3];   // (A,)

    float* out  = (float*)d_out;
    float* ctx  = out;                     // (B,H)   = 1024 floats
    float* attn = out + BATCH * HH;        // (B,S,S) = 2M floats

    float* parts     = (float*)d_ws;                          // 4 x 524288 floats
    float* P         = parts + (size_t)4 * 2048 * 256;        // 1 MB
    float* Qb        = P     + (size_t)BATCH * SB * AA;       // 1 MB
    float* rsum      = Qb    + (size_t)BATCH * SB * AA;       // 8 KB
    float* colw_part = rsum  + (size_t)BATCH * SB;            // 1 MB

    k1_gemm<<<dim3(32, 4, 4), 256, 0, stream>>>(lstm, w, u, parts, rsum, ctx);
    k1b_combine_exp<<<dim3(512), 256, 0, stream>>>(parts, P, Qb);
    k2a_escore<<<dim3(4, 128, BATCH), 256, 0, stream>>>(P, Qb, v, attn, rsum);
    k2b_scale_colpart<<<dim3(128, BATCH), 1024, 0, stream>>>(attn, rsum, colw_part);
    k4_context<<<dim3(2, 32, BATCH), 256, 0, stream>>>(lstm, colw_part, ctx);
}